// Round 1
// baseline (181.746 us; speedup 1.0000x reference)
//
#include <hip/hip_runtime.h>

typedef __bf16 bf16_t;
typedef __bf16 bf16x8 __attribute__((ext_vector_type(8)));
typedef __bf16 bf16x4 __attribute__((ext_vector_type(4)));
typedef float f32x4 __attribute__((ext_vector_type(4)));

static constexpr int kC = 256;   // channels
static constexpr int kN = 1024;  // tokens (32x32)
static constexpr int kB = 32;    // batch

// ---------------- GroupNorm stats: one block per (b,g); 8 ch x 1024 = 8192 f32 ----------------
__global__ __launch_bounds__(256) void gn_stats_k(const float* __restrict__ x,
                                                  float* __restrict__ stats) {
  const float* base = x + (size_t)blockIdx.x * 8192;  // (b*32+g)*8*1024
  int t = threadIdx.x;
  float s = 0.f, q = 0.f;
#pragma unroll
  for (int i = 0; i < 8; ++i) {
    float4 v = *(const float4*)(base + (i * 256 + t) * 4);
    s += v.x + v.y + v.z + v.w;
    q += v.x * v.x + v.y * v.y + v.z * v.z + v.w * v.w;
  }
#pragma unroll
  for (int o = 32; o; o >>= 1) { s += __shfl_down(s, o); q += __shfl_down(q, o); }
  __shared__ float rs[4], rq[4];
  int w = t >> 6;
  if ((t & 63) == 0) { rs[w] = s; rq[w] = q; }
  __syncthreads();
  if (t == 0) {
    float S = rs[0] + rs[1] + rs[2] + rs[3];
    float Q = rq[0] + rq[1] + rq[2] + rq[3];
    float mean = S * (1.f / 8192.f);
    float var = Q * (1.f / 8192.f) - mean * mean;  // biased var (ddof=0) matches jnp.var
    stats[blockIdx.x * 2] = mean;
    stats[blockIdx.x * 2 + 1] = rsqrtf(var + 1e-5f);
  }
}

// ------- GN normalize: write Hn transposed [B][N][C] bf16 via LDS transpose -------
// block = (b, ntile of 32 tokens); 256 threads
__global__ __launch_bounds__(256) void gn_norm_k(const float* __restrict__ x,
                                                 const float* __restrict__ stats,
                                                 const float* __restrict__ gamma,
                                                 const float* __restrict__ beta,
                                                 bf16_t* __restrict__ hn) {
  __shared__ float lds[32 * 265];  // [n][c] with pad 265 (odd -> spreads banks)
  __shared__ float sm[32], sr[32], sg[256], sb[256];
  int bid = blockIdx.x;
  int b = bid >> 5, nt = bid & 31;
  int n0 = nt * 32;
  int t = threadIdx.x;
  if (t < 32) {
    sm[t] = stats[(b * 32 + t) * 2];
    sr[t] = stats[(b * 32 + t) * 2 + 1];
  }
  sg[t] = gamma[t];
  sb[t] = beta[t];
  const float* xb = x + (size_t)b * (kC * kN);
#pragma unroll
  for (int i = 0; i < 8; ++i) {
    int cid = i * 256 + t;  // 2048 float4 chunks = 256c x 32n
    int c = cid >> 3, j = cid & 7;
    float4 v = *(const float4*)(xb + (size_t)c * kN + n0 + j * 4);
    lds[(4 * j + 0) * 265 + c] = v.x;
    lds[(4 * j + 1) * 265 + c] = v.y;
    lds[(4 * j + 2) * 265 + c] = v.z;
    lds[(4 * j + 3) * 265 + c] = v.w;
  }
  __syncthreads();
  bf16_t* hb = hn + (size_t)b * (kN * kC);
#pragma unroll
  for (int i = 0; i < 4; ++i) {
    int wid = i * 256 + t;  // 1024 chunks: [n][group of 8 ch] (group == c8 since 8 ch/group)
    int n = wid >> 5, c8 = wid & 31;
    float mean = sm[c8], rstd = sr[c8];
    bf16x8 o;
#pragma unroll
    for (int jj = 0; jj < 8; ++jj) {
      int c = c8 * 8 + jj;
      float v = lds[n * 265 + c];
      o[jj] = (bf16_t)((v - mean) * rstd * sg[c] + sb[c]);
    }
    *(bf16x8*)(hb + (size_t)(n0 + n) * kC + c8 * 8) = o;  // coalesced 16B stores
  }
}

// ---------------- cast the four 256x256 f32 weights to bf16 ----------------
__global__ __launch_bounds__(256) void castw_k(const float* __restrict__ wq,
                                               const float* __restrict__ wk,
                                               const float* __restrict__ wv,
                                               const float* __restrict__ wh,
                                               bf16_t* __restrict__ o) {
  int i = blockIdx.x * 256 + threadIdx.x;  // 65536 threads
  o[i] = (bf16_t)wq[i];
  o[i + 65536] = (bf16_t)wk[i];
  o[i + 131072] = (bf16_t)wv[i];
  o[i + 196608] = (bf16_t)wh[i];
}

// ---------------- in-place softmax over rows of S [B*N][N] bf16 ----------------
__global__ __launch_bounds__(256) void softmax_k(bf16_t* __restrict__ S) {
  bf16_t* p = S + (size_t)blockIdx.x * kN;
  int t = threadIdx.x;
  bf16x4 v4 = *(bf16x4*)(p + t * 4);
  float v0 = (float)v4[0], v1 = (float)v4[1], v2 = (float)v4[2], v3 = (float)v4[3];
  float m = fmaxf(fmaxf(v0, v1), fmaxf(v2, v3));
#pragma unroll
  for (int o = 32; o; o >>= 1) m = fmaxf(m, __shfl_down(m, o));
  __shared__ float r1[4], r2[4];
  int w = t >> 6;
  if ((t & 63) == 0) r1[w] = m;
  __syncthreads();
  m = fmaxf(fmaxf(r1[0], r1[1]), fmaxf(r1[2], r1[3]));
  v0 = exp2f((v0 - m) * 1.44269504f);
  v1 = exp2f((v1 - m) * 1.44269504f);
  v2 = exp2f((v2 - m) * 1.44269504f);
  v3 = exp2f((v3 - m) * 1.44269504f);
  float s = v0 + v1 + v2 + v3;
#pragma unroll
  for (int o = 32; o; o >>= 1) s += __shfl_down(s, o);
  if ((t & 63) == 0) r2[w] = s;
  __syncthreads();
  s = r2[0] + r2[1] + r2[2] + r2[3];
  float inv = 1.f / s;
  v4[0] = (bf16_t)(v0 * inv);
  v4[1] = (bf16_t)(v1 * inv);
  v4[2] = (bf16_t)(v2 * inv);
  v4[3] = (bf16_t)(v3 * inv);
  *(bf16x4*)(p + t * 4) = v4;
}

// ---------------- unified bf16 MFMA GEMM ----------------
// D[r][c] = sum_k A[r][k] * BT[c][k]   (A: [M][K] rm, BT: [Nn][K] rm)
// 128x128 tile, BK=64, 4 waves of 4x4 16x16x32 fragments, XOR-swizzled LDS.
// EPI: 0 = transposed bf16 store + bias[r]   (Dst[c*ldD + r])
//      1 = natural    bf16 store + bias[r]   (Dst[r*ldD + c])
//      2 = transposed bf16 store * scale
//      3 = natural    bf16 store
//      4 = transposed f32  store + resid + bias[c]
template <int EPI>
__global__ __launch_bounds__(256) void gemm_k(const bf16_t* __restrict__ A, long sA,
                                              const bf16_t* __restrict__ BT, long sB,
                                              void* __restrict__ Dst, long sD,
                                              const float* __restrict__ bias,
                                              const float* __restrict__ resid, long sR,
                                              int K, int ldD, int tilesM, int tilesN,
                                              float scale) {
  __shared__ bf16_t lA[128 * 64];
  __shared__ bf16_t lB[128 * 64];
  int bid = blockIdx.x;
  int tpb = tilesM * tilesN;
  int b = bid / tpb;
  int rem = bid - b * tpb;
  int tmi = rem / tilesN;
  int tni = rem - tmi * tilesN;
  const bf16_t* Ab = A + (size_t)b * sA + (size_t)tmi * 128 * K;
  const bf16_t* Bb = BT + (size_t)b * sB + (size_t)tni * 128 * K;
  int t = threadIdx.x;
  int wid = t >> 6, l = t & 63;
  int wm = wid >> 1, wn = wid & 1;
  int lr = l & 15, lk = l >> 4;
  f32x4 acc[4][4] = {};
  for (int k0 = 0; k0 < K; k0 += 64) {
    __syncthreads();
#pragma unroll
    for (int i = 0; i < 4; ++i) {
      int ci = i * 256 + t;  // 1024 chunks of 16B per tile
      int row = ci >> 3, ch = ci & 7;
      int p = ((ch ^ (row & 7)) * 8);
      *(uint4*)(lA + row * 64 + p) = *(const uint4*)(Ab + (size_t)row * K + k0 + ch * 8);
      *(uint4*)(lB + row * 64 + p) = *(const uint4*)(Bb + (size_t)row * K + k0 + ch * 8);
    }
    __syncthreads();
#pragma unroll
    for (int kk = 0; kk < 2; ++kk) {
      bf16x8 af[4], bfr[4];
#pragma unroll
      for (int mf = 0; mf < 4; ++mf) {
        int r = wm * 64 + mf * 16 + lr;
        int ch = kk * 4 + lk;
        af[mf] = *(const bf16x8*)(lA + r * 64 + ((ch ^ (r & 7)) * 8));
      }
#pragma unroll
      for (int nf = 0; nf < 4; ++nf) {
        int r = wn * 64 + nf * 16 + lr;
        int ch = kk * 4 + lk;
        bfr[nf] = *(const bf16x8*)(lB + r * 64 + ((ch ^ (r & 7)) * 8));
      }
#pragma unroll
      for (int mf = 0; mf < 4; ++mf)
#pragma unroll
        for (int nf = 0; nf < 4; ++nf)
          acc[mf][nf] = __builtin_amdgcn_mfma_f32_16x16x32_bf16(af[mf], bfr[nf],
                                                                acc[mf][nf], 0, 0, 0);
    }
  }
  // D fragment: col = lane&15 (= lr), row = (lane>>4)*4 + i (HW-verified layout)
  int rb = tmi * 128 + wm * 64;
  int cb = tni * 128 + wn * 64;
  if constexpr (EPI == 0 || EPI == 2) {
    bf16_t* D = (bf16_t*)Dst + (size_t)b * sD;
#pragma unroll
    for (int mf = 0; mf < 4; ++mf)
#pragma unroll
      for (int nf = 0; nf < 4; ++nf) {
        int r0 = rb + mf * 16 + lk * 4;
        int c = cb + nf * 16 + lr;
        bf16x4 v;
#pragma unroll
        for (int i = 0; i < 4; ++i) {
          float val = acc[mf][nf][i];
          if constexpr (EPI == 0) val += bias[r0 + i];
          else val *= scale;
          v[i] = (bf16_t)val;
        }
        *(bf16x4*)(D + (size_t)c * ldD + r0) = v;  // contiguous 8B store
      }
  } else if constexpr (EPI == 1 || EPI == 3) {
    bf16_t* D = (bf16_t*)Dst + (size_t)b * sD;
#pragma unroll
    for (int mf = 0; mf < 4; ++mf)
#pragma unroll
      for (int nf = 0; nf < 4; ++nf) {
        int r0 = rb + mf * 16 + lk * 4;
        int c = cb + nf * 16 + lr;
#pragma unroll
        for (int i = 0; i < 4; ++i) {
          float val = acc[mf][nf][i];
          if constexpr (EPI == 1) val += bias[r0 + i];
          D[(size_t)(r0 + i) * ldD + c] = (bf16_t)val;
        }
      }
  } else {  // EPI == 4
    float* D = (float*)Dst + (size_t)b * sD;
    const float* R = resid + (size_t)b * sR;
#pragma unroll
    for (int mf = 0; mf < 4; ++mf)
#pragma unroll
      for (int nf = 0; nf < 4; ++nf) {
        int r0 = rb + mf * 16 + lk * 4;
        int c = cb + nf * 16 + lr;
        float4 rv = *(const float4*)(R + (size_t)c * ldD + r0);
        float bc = bias[c];
        float4 o2 = make_float4(acc[mf][nf][0] + rv.x + bc, acc[mf][nf][1] + rv.y + bc,
                                acc[mf][nf][2] + rv.z + bc, acc[mf][nf][3] + rv.w + bc);
        *(float4*)(D + (size_t)c * ldD + r0) = o2;  // coalesced float4 store
      }
  }
}

extern "C" void kernel_launch(void* const* d_in, const int* in_sizes, int n_in,
                              void* d_out, int out_size, void* d_ws, size_t ws_size,
                              hipStream_t stream) {
  const float* x = (const float*)d_in[0];
  const float* gamma = (const float*)d_in[1];
  const float* beta = (const float*)d_in[2];
  const float* wq = (const float*)d_in[3];
  const float* bq = (const float*)d_in[4];
  const float* wk = (const float*)d_in[5];
  const float* bk = (const float*)d_in[6];
  const float* wv = (const float*)d_in[7];
  const float* bv = (const float*)d_in[8];
  const float* wh = (const float*)d_in[9];
  const float* bh = (const float*)d_in[10];
  float* out = (float*)d_out;

  char* ws = (char*)d_ws;
  // layout (bytes): HN/OT 16.78M | QT 16.78M | KT 16.78M | V 16.78M | S/P 67.1M | W 0.5M | stats 8K
  bf16_t* HN = (bf16_t*)(ws);                    // Hn_t [B][N][C]; reused as O_t after V GEMM
  bf16_t* QT = (bf16_t*)(ws + 16777216);         // Q_t [B][N][C]
  bf16_t* KT = (bf16_t*)(ws + 33554432);         // K_t [B][N][C]
  bf16_t* VV = (bf16_t*)(ws + 50331648);         // V   [B][C][N]
  bf16_t* SP = (bf16_t*)(ws + 67108864);         // S/P [B][N][N]
  bf16_t* WB = (bf16_t*)(ws + 134217728);        // Wq|Wk|Wv|Wh bf16
  float* ST = (float*)(ws + 134742016);          // per-(b,g) mean/rstd

  const long NC = (long)kN * kC;  // 262144
  const long NN = (long)kN * kN;  // 1048576
  const long CN = (long)kC * kN;

  gn_stats_k<<<kB * 32, 256, 0, stream>>>(x, ST);
  gn_norm_k<<<kB * 32, 256, 0, stream>>>(x, ST, gamma, beta, HN);
  castw_k<<<256, 256, 0, stream>>>(wq, wk, wv, wh, WB);

  // Q_t[n][co] = (Wq . Hn)^T + bq   (M=256 co, Nn=1024 n, K=256)
  gemm_k<0><<<kB * 2 * 8, 256, 0, stream>>>(WB, 0, HN, NC, QT, NC, bq, nullptr, 0,
                                            256, 256, 2, 8, 1.f);
  gemm_k<0><<<kB * 2 * 8, 256, 0, stream>>>(WB + 65536, 0, HN, NC, KT, NC, bk, nullptr, 0,
                                            256, 256, 2, 8, 1.f);
  // V[co][n] natural
  gemm_k<1><<<kB * 2 * 8, 256, 0, stream>>>(WB + 131072, 0, HN, NC, VV, CN, bv, nullptr, 0,
                                            256, 1024, 2, 8, 1.f);
  // S[n][m] = (K_t . Q_t^T)^T / 16   (M=1024 m, Nn=1024 n, K=256)
  gemm_k<2><<<kB * 8 * 8, 256, 0, stream>>>(KT, NC, QT, NC, SP, NN, nullptr, nullptr, 0,
                                            256, 1024, 8, 8, 0.0625f);
  softmax_k<<<kB * kN, 256, 0, stream>>>(SP);
  // O_t[n][c] = P . V^T   (M=1024 n, Nn=256 c, K=1024)  -> reuse HN buffer
  gemm_k<3><<<kB * 8 * 2, 256, 0, stream>>>(SP, NN, VV, NC, HN, NC, nullptr, nullptr, 0,
                                            1024, 256, 8, 2, 1.f);
  // out[co][n] = x + (O_t . Wh^T)^T + bh   (M=1024 n, Nn=256 co, K=256)
  gemm_k<4><<<kB * 8 * 2, 256, 0, stream>>>(HN, NC, WB + 196608, 0, out, CN, bh, x, CN,
                                            256, 1024, 8, 2, 1.f);
}

// Round 2
// 155.306 us; speedup vs baseline: 1.1702x; 1.1702x over previous
//
#include <hip/hip_runtime.h>

typedef __bf16 bf16_t;
typedef __bf16 bf16x8 __attribute__((ext_vector_type(8)));
typedef __bf16 bf16x4 __attribute__((ext_vector_type(4)));
typedef float f32x4 __attribute__((ext_vector_type(4)));

static constexpr int kC = 256;   // channels
static constexpr int kN = 1024;  // tokens (32x32)
static constexpr int kB = 32;    // batch

// ---------------- GroupNorm stats: one block per (b,g); 8 ch x 1024 = 8192 f32 ----------------
__global__ __launch_bounds__(256) void gn_stats_k(const float* __restrict__ x,
                                                  float* __restrict__ stats) {
  const float* base = x + (size_t)blockIdx.x * 8192;  // (b*32+g)*8*1024
  int t = threadIdx.x;
  float s = 0.f, q = 0.f;
#pragma unroll
  for (int i = 0; i < 8; ++i) {
    float4 v = *(const float4*)(base + (i * 256 + t) * 4);
    s += v.x + v.y + v.z + v.w;
    q += v.x * v.x + v.y * v.y + v.z * v.z + v.w * v.w;
  }
#pragma unroll
  for (int o = 32; o; o >>= 1) { s += __shfl_down(s, o); q += __shfl_down(q, o); }
  __shared__ float rs[4], rq[4];
  int w = t >> 6;
  if ((t & 63) == 0) { rs[w] = s; rq[w] = q; }
  __syncthreads();
  if (t == 0) {
    float S = rs[0] + rs[1] + rs[2] + rs[3];
    float Q = rq[0] + rq[1] + rq[2] + rq[3];
    float mean = S * (1.f / 8192.f);
    float var = Q * (1.f / 8192.f) - mean * mean;  // biased var (ddof=0) matches jnp.var
    stats[blockIdx.x * 2] = mean;
    stats[blockIdx.x * 2 + 1] = rsqrtf(var + 1e-5f);
  }
}

// ------- GN normalize: write Hn transposed [B][N][C] bf16 via LDS transpose -------
__global__ __launch_bounds__(256) void gn_norm_k(const float* __restrict__ x,
                                                 const float* __restrict__ stats,
                                                 const float* __restrict__ gamma,
                                                 const float* __restrict__ beta,
                                                 bf16_t* __restrict__ hn) {
  __shared__ float lds[32 * 265];
  __shared__ float sm[32], sr[32], sg[256], sb[256];
  int bid = blockIdx.x;
  int b = bid >> 5, nt = bid & 31;
  int n0 = nt * 32;
  int t = threadIdx.x;
  if (t < 32) {
    sm[t] = stats[(b * 32 + t) * 2];
    sr[t] = stats[(b * 32 + t) * 2 + 1];
  }
  sg[t] = gamma[t];
  sb[t] = beta[t];
  const float* xb = x + (size_t)b * (kC * kN);
#pragma unroll
  for (int i = 0; i < 8; ++i) {
    int cid = i * 256 + t;  // 2048 float4 chunks = 256c x 32n
    int c = cid >> 3, j = cid & 7;
    float4 v = *(const float4*)(xb + (size_t)c * kN + n0 + j * 4);
    lds[(4 * j + 0) * 265 + c] = v.x;
    lds[(4 * j + 1) * 265 + c] = v.y;
    lds[(4 * j + 2) * 265 + c] = v.z;
    lds[(4 * j + 3) * 265 + c] = v.w;
  }
  __syncthreads();
  bf16_t* hb = hn + (size_t)b * (kN * kC);
#pragma unroll
  for (int i = 0; i < 4; ++i) {
    int wid = i * 256 + t;
    int n = wid >> 5, c8 = wid & 31;
    float mean = sm[c8], rstd = sr[c8];
    bf16x8 o;
#pragma unroll
    for (int jj = 0; jj < 8; ++jj) {
      int c = c8 * 8 + jj;
      float v = lds[n * 265 + c];
      o[jj] = (bf16_t)((v - mean) * rstd * sg[c] + sb[c]);
    }
    *(bf16x8*)(hb + (size_t)(n0 + n) * kC + c8 * 8) = o;
  }
}

// ---------------- cast the four 256x256 f32 weights to bf16 ----------------
__global__ __launch_bounds__(256) void castw_k(const float* __restrict__ wq,
                                               const float* __restrict__ wk,
                                               const float* __restrict__ wv,
                                               const float* __restrict__ wh,
                                               bf16_t* __restrict__ o) {
  int i = blockIdx.x * 256 + threadIdx.x;
  o[i] = (bf16_t)wq[i];
  o[i + 65536] = (bf16_t)wk[i];
  o[i + 131072] = (bf16_t)wv[i];
  o[i + 196608] = (bf16_t)wh[i];
}

// ---------------- fused flash attention ----------------
// QT, KT: [B][N][C] token-major bf16 (bias already applied). VV: [B][C][N].
// OT out: [B][N][C] bf16, softmax(QK^T/16) V.
// grid = B*8 (128-token Q tiles); 512 threads = 8 waves; wave owns 16 Q rows.
__global__ __launch_bounds__(512, 2) void fattn_k(const bf16_t* __restrict__ QT,
                                                  const bf16_t* __restrict__ KT,
                                                  const bf16_t* __restrict__ VV,
                                                  bf16_t* __restrict__ OT) {
  __shared__ bf16_t lK[64 * 256];    // [kv][c], 16B-chunk slot = ch ^ (row&7), ch=c/8 (0..31)
  __shared__ bf16_t lV[256 * 64];    // [c][kv], slot = ch ^ (c&7), ch=k/8 (0..7)
  __shared__ bf16_t lP[8][16 * 64];  // per-wave P [qrow][k], slot = ch ^ (row&7)

  int bid = blockIdx.x;
  int b = bid >> 3, qt = bid & 7;
  int t = threadIdx.x, wid = t >> 6, lane = t & 63;
  int lr = lane & 15, lk = lane >> 4;
  const bf16_t* Qb = QT + (size_t)b * (kN * kC);
  const bf16_t* Kb = KT + (size_t)b * (kN * kC);
  const bf16_t* Vb = VV + (size_t)b * (kC * kN);
  int q0 = qt * 128 + wid * 16;

  // hoist Q fragments: qf[kf] holds Q[q0+lr][kf*32 + lk*8 + j]
  bf16x8 qf[8];
#pragma unroll
  for (int kf = 0; kf < 8; ++kf)
    qf[kf] = *(const bf16x8*)(Qb + (size_t)(q0 + lr) * kC + kf * 32 + lk * 8);

  f32x4 acc[16] = {};  // O acc: (row=lk*4+i, col=cf*16+lr)
  float m_i[4], l_i[4];
#pragma unroll
  for (int i = 0; i < 4; ++i) { m_i[i] = -1e30f; l_i[i] = 0.f; }

  for (int k0 = 0; k0 < kN; k0 += 64) {
    __syncthreads();  // previous tile fully consumed
    // stage K (2048 chunks of 16B) + V (2048 chunks); 4 chunks each per thread
#pragma unroll
    for (int i = 0; i < 4; ++i) {
      int ck = i * 512 + t;
      int row = ck >> 5, ch = ck & 31;       // K: row=kv token, 32 chunks/row
      uint4 vk = *(const uint4*)(Kb + (size_t)(k0 + row) * kC + ((ch ^ (row & 7)) << 3));
      *(uint4*)(lK + (ck << 3)) = vk;
      int rv = ck >> 3, cv = ck & 7;         // V: row=channel, 8 chunks/row
      uint4 vv = *(const uint4*)(Vb + (size_t)rv * kN + k0 + ((cv ^ (rv & 7)) << 3));
      *(uint4*)(lV + (ck << 3)) = vv;
    }
    __syncthreads();

    // S = Q K^T (16 x 64 per wave), f32 accum
    f32x4 s[4] = {};
#pragma unroll
    for (int kf = 0; kf < 8; ++kf) {
#pragma unroll
      for (int nf = 0; nf < 4; ++nf) {
        int r = nf * 16 + lr;
        int ch = kf * 4 + lk;
        bf16x8 bk8 = *(const bf16x8*)(lK + r * 256 + ((ch ^ (r & 7)) << 3));
        s[nf] = __builtin_amdgcn_mfma_f32_16x16x32_bf16(qf[kf], bk8, s[nf], 0, 0, 0);
      }
    }
    // scale 1/sqrt(256)
#pragma unroll
    for (int nf = 0; nf < 4; ++nf)
#pragma unroll
      for (int i = 0; i < 4; ++i) s[nf][i] *= 0.0625f;

    // online softmax: rows are lane-groups (row = lk*4+i); reduce over lr bits
    float pm[4];
#pragma unroll
    for (int i = 0; i < 4; ++i)
      pm[i] = fmaxf(fmaxf(s[0][i], s[1][i]), fmaxf(s[2][i], s[3][i]));
#pragma unroll
    for (int i = 0; i < 4; ++i) {
      pm[i] = fmaxf(pm[i], __shfl_xor(pm[i], 1));
      pm[i] = fmaxf(pm[i], __shfl_xor(pm[i], 2));
      pm[i] = fmaxf(pm[i], __shfl_xor(pm[i], 4));
      pm[i] = fmaxf(pm[i], __shfl_xor(pm[i], 8));
    }
    float al[4];
#pragma unroll
    for (int i = 0; i < 4; ++i) {
      float mn = fmaxf(m_i[i], pm[i]);
      al[i] = exp2f((m_i[i] - mn) * 1.44269504f);
      m_i[i] = mn;
    }
    float rsum[4] = {0.f, 0.f, 0.f, 0.f};
#pragma unroll
    for (int nf = 0; nf < 4; ++nf)
#pragma unroll
      for (int i = 0; i < 4; ++i) {
        float p = exp2f((s[nf][i] - m_i[i]) * 1.44269504f);
        s[nf][i] = p;
        rsum[i] += p;
      }
#pragma unroll
    for (int i = 0; i < 4; ++i) {
      rsum[i] += __shfl_xor(rsum[i], 1);
      rsum[i] += __shfl_xor(rsum[i], 2);
      rsum[i] += __shfl_xor(rsum[i], 4);
      rsum[i] += __shfl_xor(rsum[i], 8);
      l_i[i] = l_i[i] * al[i] + rsum[i];
    }
    // rescale O accumulator
#pragma unroll
    for (int cf = 0; cf < 16; ++cf)
#pragma unroll
      for (int i = 0; i < 4; ++i) acc[cf][i] *= al[i];

    // P -> wave-private LDS (bf16), C/D layout -> A layout round trip
    bf16_t* Pw = &lP[wid][0];
#pragma unroll
    for (int nf = 0; nf < 4; ++nf)
#pragma unroll
      for (int i = 0; i < 4; ++i) {
        int row = lk * 4 + i, col = nf * 16 + lr;
        Pw[row * 64 + (((col >> 3) ^ (row & 7)) << 3) + (col & 7)] = (bf16_t)s[nf][i];
      }
    // PV: acc[cf] += P[16x64] * V[64 x 256]
#pragma unroll
    for (int kk = 0; kk < 2; ++kk) {
      int ch = kk * 4 + lk;
      bf16x8 pa = *(const bf16x8*)(Pw + lr * 64 + ((ch ^ (lr & 7)) << 3));
#pragma unroll
      for (int cf = 0; cf < 16; ++cf) {
        int r = cf * 16 + lr;
        bf16x8 bv8 = *(const bf16x8*)(lV + r * 64 + ((ch ^ (r & 7)) << 3));
        acc[cf] = __builtin_amdgcn_mfma_f32_16x16x32_bf16(pa, bv8, acc[cf], 0, 0, 0);
      }
    }
  }

  // epilogue: normalize by 1/l and store O_t[n][c]
  bf16_t* Ob = OT + (size_t)b * (kN * kC);
#pragma unroll
  for (int i = 0; i < 4; ++i) {
    float inv = 1.f / l_i[i];
    size_t q = q0 + lk * 4 + i;
#pragma unroll
    for (int cf = 0; cf < 16; ++cf)
      Ob[q * kC + cf * 16 + lr] = (bf16_t)(acc[cf][i] * inv);
  }
}

// ---------------- unified bf16 MFMA GEMM (unchanged from R0) ----------------
// D[r][c] = sum_k A[r][k] * BT[c][k]
// EPI: 0 = transposed bf16 store + bias[r]; 1 = natural bf16 store + bias[r];
//      4 = transposed f32 store + resid + bias[c]
template <int EPI>
__global__ __launch_bounds__(256) void gemm_k(const bf16_t* __restrict__ A, long sA,
                                              const bf16_t* __restrict__ BT, long sB,
                                              void* __restrict__ Dst, long sD,
                                              const float* __restrict__ bias,
                                              const float* __restrict__ resid, long sR,
                                              int K, int ldD, int tilesM, int tilesN,
                                              float scale) {
  __shared__ bf16_t lA[128 * 64];
  __shared__ bf16_t lB[128 * 64];
  int bid = blockIdx.x;
  int tpb = tilesM * tilesN;
  int b = bid / tpb;
  int rem = bid - b * tpb;
  int tmi = rem / tilesN;
  int tni = rem - tmi * tilesN;
  const bf16_t* Ab = A + (size_t)b * sA + (size_t)tmi * 128 * K;
  const bf16_t* Bb = BT + (size_t)b * sB + (size_t)tni * 128 * K;
  int t = threadIdx.x;
  int wid = t >> 6, l = t & 63;
  int wm = wid >> 1, wn = wid & 1;
  int lr = l & 15, lk = l >> 4;
  f32x4 acc[4][4] = {};
  for (int k0 = 0; k0 < K; k0 += 64) {
    __syncthreads();
#pragma unroll
    for (int i = 0; i < 4; ++i) {
      int ci = i * 256 + t;
      int row = ci >> 3, ch = ci & 7;
      int p = ((ch ^ (row & 7)) * 8);
      *(uint4*)(lA + row * 64 + p) = *(const uint4*)(Ab + (size_t)row * K + k0 + ch * 8);
      *(uint4*)(lB + row * 64 + p) = *(const uint4*)(Bb + (size_t)row * K + k0 + ch * 8);
    }
    __syncthreads();
#pragma unroll
    for (int kk = 0; kk < 2; ++kk) {
      bf16x8 af[4], bfr[4];
#pragma unroll
      for (int mf = 0; mf < 4; ++mf) {
        int r = wm * 64 + mf * 16 + lr;
        int ch = kk * 4 + lk;
        af[mf] = *(const bf16x8*)(lA + r * 64 + ((ch ^ (r & 7)) * 8));
      }
#pragma unroll
      for (int nf = 0; nf < 4; ++nf) {
        int r = wn * 64 + nf * 16 + lr;
        int ch = kk * 4 + lk;
        bfr[nf] = *(const bf16x8*)(lB + r * 64 + ((ch ^ (r & 7)) * 8));
      }
#pragma unroll
      for (int mf = 0; mf < 4; ++mf)
#pragma unroll
        for (int nf = 0; nf < 4; ++nf)
          acc[mf][nf] = __builtin_amdgcn_mfma_f32_16x16x32_bf16(af[mf], bfr[nf],
                                                                acc[mf][nf], 0, 0, 0);
    }
  }
  int rb = tmi * 128 + wm * 64;
  int cb = tni * 128 + wn * 64;
  if constexpr (EPI == 0) {
    bf16_t* D = (bf16_t*)Dst + (size_t)b * sD;
#pragma unroll
    for (int mf = 0; mf < 4; ++mf)
#pragma unroll
      for (int nf = 0; nf < 4; ++nf) {
        int r0 = rb + mf * 16 + lk * 4;
        int c = cb + nf * 16 + lr;
        bf16x4 v;
#pragma unroll
        for (int i = 0; i < 4; ++i) v[i] = (bf16_t)(acc[mf][nf][i] + bias[r0 + i]);
        *(bf16x4*)(D + (size_t)c * ldD + r0) = v;
      }
  } else if constexpr (EPI == 1) {
    bf16_t* D = (bf16_t*)Dst + (size_t)b * sD;
#pragma unroll
    for (int mf = 0; mf < 4; ++mf)
#pragma unroll
      for (int nf = 0; nf < 4; ++nf) {
        int r0 = rb + mf * 16 + lk * 4;
        int c = cb + nf * 16 + lr;
#pragma unroll
        for (int i = 0; i < 4; ++i)
          D[(size_t)(r0 + i) * ldD + c] = (bf16_t)(acc[mf][nf][i] + bias[r0 + i]);
      }
  } else {  // EPI == 4
    float* D = (float*)Dst + (size_t)b * sD;
    const float* R = resid + (size_t)b * sR;
#pragma unroll
    for (int mf = 0; mf < 4; ++mf)
#pragma unroll
      for (int nf = 0; nf < 4; ++nf) {
        int r0 = rb + mf * 16 + lk * 4;
        int c = cb + nf * 16 + lr;
        float4 rv = *(const float4*)(R + (size_t)c * ldD + r0);
        float bc = bias[c];
        float4 o2 = make_float4(acc[mf][nf][0] + rv.x + bc, acc[mf][nf][1] + rv.y + bc,
                                acc[mf][nf][2] + rv.z + bc, acc[mf][nf][3] + rv.w + bc);
        *(float4*)(D + (size_t)c * ldD + r0) = o2;
      }
  }
}

extern "C" void kernel_launch(void* const* d_in, const int* in_sizes, int n_in,
                              void* d_out, int out_size, void* d_ws, size_t ws_size,
                              hipStream_t stream) {
  const float* x = (const float*)d_in[0];
  const float* gamma = (const float*)d_in[1];
  const float* beta = (const float*)d_in[2];
  const float* wq = (const float*)d_in[3];
  const float* bq = (const float*)d_in[4];
  const float* wk = (const float*)d_in[5];
  const float* bk = (const float*)d_in[6];
  const float* wv = (const float*)d_in[7];
  const float* bv = (const float*)d_in[8];
  const float* wh = (const float*)d_in[9];
  const float* bh = (const float*)d_in[10];
  float* out = (float*)d_out;

  char* ws = (char*)d_ws;
  bf16_t* HN = (bf16_t*)(ws);                // Hn_t [B][N][C]; reused as O_t after fattn
  bf16_t* QT = (bf16_t*)(ws + 16777216);     // Q_t [B][N][C]
  bf16_t* KT = (bf16_t*)(ws + 33554432);     // K_t [B][N][C]
  bf16_t* VV = (bf16_t*)(ws + 50331648);     // V   [B][C][N]
  bf16_t* WB = (bf16_t*)(ws + 67108864);     // Wq|Wk|Wv|Wh bf16
  float* ST = (float*)(ws + 67633152);       // per-(b,g) mean/rstd

  const long NC = (long)kN * kC;
  const long CN = (long)kC * kN;

  gn_stats_k<<<kB * 32, 256, 0, stream>>>(x, ST);
  gn_norm_k<<<kB * 32, 256, 0, stream>>>(x, ST, gamma, beta, HN);
  castw_k<<<256, 256, 0, stream>>>(wq, wk, wv, wh, WB);

  // Q_t[n][co] = (Wq . Hn)^T + bq
  gemm_k<0><<<kB * 2 * 8, 256, 0, stream>>>(WB, 0, HN, NC, QT, NC, bq, nullptr, 0,
                                            256, 256, 2, 8, 1.f);
  gemm_k<0><<<kB * 2 * 8, 256, 0, stream>>>(WB + 65536, 0, HN, NC, KT, NC, bk, nullptr, 0,
                                            256, 256, 2, 8, 1.f);
  // V[co][n]
  gemm_k<1><<<kB * 2 * 8, 256, 0, stream>>>(WB + 131072, 0, HN, NC, VV, CN, bv, nullptr, 0,
                                            256, 1024, 2, 8, 1.f);
  // fused attention -> O_t in HN
  fattn_k<<<kB * 8, 512, 0, stream>>>(QT, KT, VV, HN);
  // out[co][n] = x + (O_t . Wh^T)^T + bh
  gemm_k<4><<<kB * 8 * 2, 256, 0, stream>>>(HN, NC, WB + 196608, 0, out, CN, bh, x, CN,
                                            256, 1024, 8, 2, 1.f);
}

// Round 3
// 149.432 us; speedup vs baseline: 1.2162x; 1.0393x over previous
//
#include <hip/hip_runtime.h>

typedef __bf16 bf16_t;
typedef __bf16 bf16x8 __attribute__((ext_vector_type(8)));
typedef __bf16 bf16x4 __attribute__((ext_vector_type(4)));
typedef float f32x4 __attribute__((ext_vector_type(4)));
typedef float f32x16 __attribute__((ext_vector_type(16)));

static constexpr int kC = 256;   // channels
static constexpr int kN = 1024;  // tokens (32x32)
static constexpr int kB = 32;    // batch

__device__ __forceinline__ void gload_lds16(const bf16_t* g, bf16_t* l) {
  __builtin_amdgcn_global_load_lds(
      (const __attribute__((address_space(1))) unsigned int*)g,
      (__attribute__((address_space(3))) unsigned int*)l, 16, 0, 0);
}

__device__ __forceinline__ unsigned cvt_pk_bf16(float a, float b) {
  unsigned r;
  asm("v_cvt_pk_bf16_f32 %0, %1, %2" : "=v"(r) : "v"(a), "v"(b));
  return r;
}

// ------- fused GroupNorm: one block per (b,g); stats + normalize in one x read -------
__global__ __launch_bounds__(256) void gn_fused_k(const float* __restrict__ x,
                                                  const float* __restrict__ gamma,
                                                  const float* __restrict__ beta,
                                                  bf16_t* __restrict__ hn) {
  __shared__ float xs[8 * 1040];  // [c_local][n] pad 1040 (16-float pad)
  __shared__ float red[8];
  __shared__ float stat[2];
  int bg = blockIdx.x;
  int b = bg >> 5, g = bg & 31;
  int t = threadIdx.x;
  const float* base = x + (size_t)bg * 8192;
  float s = 0.f, q = 0.f;
#pragma unroll
  for (int i = 0; i < 8; ++i) {
    float4 v = *(const float4*)(base + i * 1024 + t * 4);
    *(float4*)(xs + i * 1040 + t * 4) = v;
    s += v.x + v.y + v.z + v.w;
    q += v.x * v.x + v.y * v.y + v.z * v.z + v.w * v.w;
  }
#pragma unroll
  for (int o = 32; o; o >>= 1) { s += __shfl_down(s, o); q += __shfl_down(q, o); }
  int w = t >> 6;
  if ((t & 63) == 0) { red[w] = s; red[4 + w] = q; }
  __syncthreads();
  if (t == 0) {
    float S = red[0] + red[1] + red[2] + red[3];
    float Q = red[4] + red[5] + red[6] + red[7];
    float mean = S * (1.f / 8192.f);
    float var = Q * (1.f / 8192.f) - mean * mean;  // biased var matches jnp.var
    stat[0] = mean;
    stat[1] = rsqrtf(var + 1e-5f);
  }
  __syncthreads();
  float mean = stat[0], rstd = stat[1];
  float gmb[8], btb[8];
#pragma unroll
  for (int j = 0; j < 8; ++j) { gmb[j] = gamma[g * 8 + j]; btb[j] = beta[g * 8 + j]; }
  bf16_t* hb = hn + (size_t)b * (kN * kC) + g * 8;
#pragma unroll
  for (int i = 0; i < 4; ++i) {
    int n = i * 256 + t;
    bf16x8 o;
#pragma unroll
    for (int j = 0; j < 8; ++j)
      o[j] = (bf16_t)((xs[j * 1040 + n] - mean) * rstd * gmb[j] + btb[j]);
    *(bf16x8*)(hb + (size_t)n * kC) = o;
  }
}

// ---------------- cast the four 256x256 f32 weights to bf16 ----------------
__global__ __launch_bounds__(256) void castw_k(const float* __restrict__ wq,
                                               const float* __restrict__ wk,
                                               const float* __restrict__ wv,
                                               const float* __restrict__ wh,
                                               bf16_t* __restrict__ o) {
  int i = blockIdx.x * 256 + threadIdx.x;
  o[i] = (bf16_t)wq[i];
  o[i + 65536] = (bf16_t)wk[i];
  o[i + 131072] = (bf16_t)wv[i];
  o[i + 196608] = (bf16_t)wh[i];
}

// ---------------- fused flash attention, 32x32 MFMA, swapped QK^T ----------------
// QT, KT: [B][N][C] token-major bf16 (bias applied). VV: [B][C][N].
// OT: [B][N][C] bf16 = softmax(QK^T/16) V.
// grid = 256 (b,qtile swizzled for XCD L2 reuse); 4 waves x 32 Q-rows = 128 Q/block.
__global__ __launch_bounds__(256, 1) void fattn_k(const bf16_t* __restrict__ QT,
                                                  const bf16_t* __restrict__ KT,
                                                  const bf16_t* __restrict__ VV,
                                                  bf16_t* __restrict__ OT) {
  __shared__ bf16_t lK[2][64 * 256];  // [kv][C], 16B-chunk slot = ch ^ (row&31)
  __shared__ bf16_t lV[2][256 * 64];  // [c][kv], 16B-chunk slot = ch ^ (c&7)
  int t = threadIdx.x;
  int wid = t >> 6, lane = t & 63;
  int l31 = lane & 31, hi = lane >> 5;
  int bid = blockIdx.x;
  // XCD swizzle: batches {4x..4x+3} -> XCD x (assuming round-robin bid%8 -> XCD)
  int b = ((bid & 7) << 2) | ((bid >> 3) & 3);
  int qt = bid >> 5;
  const bf16_t* Qb = QT + (size_t)b * (kN * kC);
  const bf16_t* Kb = KT + (size_t)b * (kN * kC);
  const bf16_t* Vb = VV + (size_t)b * (kC * kN);
  int q0 = qt * 128 + wid * 32;

  // hoist Q (B-operand): qf[ks] = Q[q0 + l31][ks*16 + hi*8 .. +7]
  bf16x8 qf[16];
#pragma unroll
  for (int ks = 0; ks < 16; ++ks)
    qf[ks] = *(const bf16x8*)(Qb + (size_t)(q0 + l31) * kC + ks * 16 + hi * 8);

  f32x16 acc[8] = {};  // O[q][c]: col c = ct*32+l31, row q = (r&3)+8*(r>>2)+4*hi
  float m = -1e30f, lsum = 0.f;

  auto STAGE = [&](int buf, int k0) {
    if (wid < 2) {  // K tile: 32 chunks of 1KB (2 rows each)
#pragma unroll
      for (int i = 0; i < 16; ++i) {
        int ck = wid * 16 + i;
        int r = ck * 2 + hi;  // per-lane row
        gload_lds16(Kb + (size_t)(k0 + r) * kC + ((l31 ^ (r & 31)) << 3),
                    &lK[buf][ck * 512]);
      }
    } else {  // V tile: 32 chunks of 1KB (8 c-rows each)
#pragma unroll
      for (int i = 0; i < 16; ++i) {
        int cv = (wid - 2) * 16 + i;
        int c = cv * 8 + (lane >> 3);
        gload_lds16(Vb + (size_t)c * kN + k0 + (((lane & 7) ^ (c & 7)) << 3),
                    &lV[buf][cv * 512]);
      }
    }
  };

  auto COMPUTE = [&](int buf) {
    const bf16_t* bK = lK[buf];
    const bf16_t* bV = lV[buf];
    // S^T = K . Q^T : two 32x32 tiles (kv 0-31, 32-63), f32 accum
    f32x16 sA = {}, sB = {};
#pragma unroll
    for (int ks = 0; ks < 16; ++ks) {
      bf16x8 k0f = *(const bf16x8*)(bK + l31 * 256 + (((2 * ks + hi) ^ l31) << 3));
      sA = __builtin_amdgcn_mfma_f32_32x32x16_bf16(k0f, qf[ks], sA, 0, 0, 0);
      bf16x8 k1f = *(const bf16x8*)(bK + (32 + l31) * 256 + (((2 * ks + hi) ^ l31) << 3));
      sB = __builtin_amdgcn_mfma_f32_32x32x16_bf16(k1f, qf[ks], sB, 0, 0, 0);
    }
#pragma unroll
    for (int r = 0; r < 16; ++r) { sA[r] *= 0.0625f; sB[r] *= 0.0625f; }
    // online softmax over kv (S^T rows): in-lane regs + cross-half swap
    float pmax = sA[0];
#pragma unroll
    for (int r = 1; r < 16; ++r) pmax = fmaxf(pmax, sA[r]);
#pragma unroll
    for (int r = 0; r < 16; ++r) pmax = fmaxf(pmax, sB[r]);
    pmax = fmaxf(pmax, __shfl_xor(pmax, 32));
    if (!__all(pmax - m <= 8.0f)) {  // defer-max (T13)
      float mn = fmaxf(m, pmax);
      float al = exp2f((m - mn) * 1.44269504f);
      m = mn;
      lsum *= al;
#pragma unroll
      for (int ct = 0; ct < 8; ++ct) acc[ct] = acc[ct] * al;
    }
    float rs = 0.f;
#pragma unroll
    for (int r = 0; r < 16; ++r) {
      float p = exp2f((sA[r] - m) * 1.44269504f);
      sA[r] = p; rs += p;
      float p2 = exp2f((sB[r] - m) * 1.44269504f);
      sB[r] = p2; rs += p2;
    }
    rs += __shfl_xor(rs, 32);
    lsum += rs;
    // P -> A-frags in-register (cvt_pk + shfl_xor(32)), then PV
    unsigned pw[4][4];
    {
      unsigned A0 = cvt_pk_bf16(sA[0], sA[1]), A1 = cvt_pk_bf16(sA[2], sA[3]);
      unsigned B0 = cvt_pk_bf16(sA[4], sA[5]), B1 = cvt_pk_bf16(sA[6], sA[7]);
      unsigned C0 = cvt_pk_bf16(sA[8], sA[9]), C1 = cvt_pk_bf16(sA[10], sA[11]);
      unsigned D0 = cvt_pk_bf16(sA[12], sA[13]), D1 = cvt_pk_bf16(sA[14], sA[15]);
      unsigned xA0 = __shfl_xor((int)A0, 32), xA1 = __shfl_xor((int)A1, 32);
      unsigned xB0 = __shfl_xor((int)B0, 32), xB1 = __shfl_xor((int)B1, 32);
      unsigned xC0 = __shfl_xor((int)C0, 32), xC1 = __shfl_xor((int)C1, 32);
      unsigned xD0 = __shfl_xor((int)D0, 32), xD1 = __shfl_xor((int)D1, 32);
      pw[0][0] = hi ? xB0 : A0; pw[0][1] = hi ? xB1 : A1;
      pw[0][2] = hi ? B0 : xA0; pw[0][3] = hi ? B1 : xA1;
      pw[1][0] = hi ? xD0 : C0; pw[1][1] = hi ? xD1 : C1;
      pw[1][2] = hi ? D0 : xC0; pw[1][3] = hi ? D1 : xC1;
    }
    {
      unsigned A0 = cvt_pk_bf16(sB[0], sB[1]), A1 = cvt_pk_bf16(sB[2], sB[3]);
      unsigned B0 = cvt_pk_bf16(sB[4], sB[5]), B1 = cvt_pk_bf16(sB[6], sB[7]);
      unsigned C0 = cvt_pk_bf16(sB[8], sB[9]), C1 = cvt_pk_bf16(sB[10], sB[11]);
      unsigned D0 = cvt_pk_bf16(sB[12], sB[13]), D1 = cvt_pk_bf16(sB[14], sB[15]);
      unsigned xA0 = __shfl_xor((int)A0, 32), xA1 = __shfl_xor((int)A1, 32);
      unsigned xB0 = __shfl_xor((int)B0, 32), xB1 = __shfl_xor((int)B1, 32);
      unsigned xC0 = __shfl_xor((int)C0, 32), xC1 = __shfl_xor((int)C1, 32);
      unsigned xD0 = __shfl_xor((int)D0, 32), xD1 = __shfl_xor((int)D1, 32);
      pw[2][0] = hi ? xB0 : A0; pw[2][1] = hi ? xB1 : A1;
      pw[2][2] = hi ? B0 : xA0; pw[2][3] = hi ? B1 : xA1;
      pw[3][0] = hi ? xD0 : C0; pw[3][1] = hi ? xD1 : C1;
      pw[3][2] = hi ? D0 : xC0; pw[3][3] = hi ? D1 : xC1;
    }
#pragma unroll
    for (int ks2 = 0; ks2 < 4; ++ks2) {
      uint4 uu = make_uint4(pw[ks2][0], pw[ks2][1], pw[ks2][2], pw[ks2][3]);
      bf16x8 paf = __builtin_bit_cast(bf16x8, uu);
#pragma unroll
      for (int ct = 0; ct < 8; ++ct) {
        int c = ct * 32 + l31;
        bf16x8 vf = *(const bf16x8*)(bV + c * 64 + (((2 * ks2 + hi) ^ (c & 7)) << 3));
        acc[ct] = __builtin_amdgcn_mfma_f32_32x32x16_bf16(paf, vf, acc[ct], 0, 0, 0);
      }
    }
  };

  STAGE(0, 0);
  for (int kt = 0; kt < 15; ++kt) {
    STAGE((kt + 1) & 1, (kt + 1) * 64);  // prefetch next tile
    asm volatile("s_waitcnt vmcnt(16)" ::: "memory");  // own tile-kt loads landed
    __builtin_amdgcn_s_barrier();
    COMPUTE(kt & 1);
    __builtin_amdgcn_s_barrier();  // all waves done reading before next overwrite
  }
  asm volatile("s_waitcnt vmcnt(0)" ::: "memory");
  __builtin_amdgcn_s_barrier();
  COMPUTE(1);

  // epilogue: normalize rows and store O_t[n][c]
  float inv = 1.f / lsum;
  float invr[16];
#pragma unroll
  for (int r = 0; r < 16; ++r)
    invr[r] = __shfl(inv, (r & 3) + 8 * (r >> 2) + 4 * hi);
  bf16_t* Ob = OT + (size_t)b * (kN * kC);
#pragma unroll
  for (int ct = 0; ct < 8; ++ct)
#pragma unroll
    for (int r = 0; r < 16; ++r) {
      int qr = (r & 3) + 8 * (r >> 2) + 4 * hi;
      Ob[(size_t)(q0 + qr) * kC + ct * 32 + l31] = (bf16_t)(acc[ct][r] * invr[r]);
    }
}

// ---------------- unified bf16 MFMA GEMM (unchanged, HW-verified) ----------------
// D[r][c] = sum_k A[r][k] * BT[c][k]
template <int EPI>
__global__ __launch_bounds__(256) void gemm_k(const bf16_t* __restrict__ A, long sA,
                                              const bf16_t* __restrict__ BT, long sB,
                                              void* __restrict__ Dst, long sD,
                                              const float* __restrict__ bias,
                                              const float* __restrict__ resid, long sR,
                                              int K, int ldD, int tilesM, int tilesN,
                                              float scale) {
  __shared__ bf16_t lA[128 * 64];
  __shared__ bf16_t lB[128 * 64];
  int bid = blockIdx.x;
  int tpb = tilesM * tilesN;
  int b = bid / tpb;
  int rem = bid - b * tpb;
  int tmi = rem / tilesN;
  int tni = rem - tmi * tilesN;
  const bf16_t* Ab = A + (size_t)b * sA + (size_t)tmi * 128 * K;
  const bf16_t* Bb = BT + (size_t)b * sB + (size_t)tni * 128 * K;
  int t = threadIdx.x;
  int wid = t >> 6, l = t & 63;
  int wm = wid >> 1, wn = wid & 1;
  int lr = l & 15, lk = l >> 4;
  f32x4 acc[4][4] = {};
  for (int k0 = 0; k0 < K; k0 += 64) {
    __syncthreads();
#pragma unroll
    for (int i = 0; i < 4; ++i) {
      int ci = i * 256 + t;
      int row = ci >> 3, ch = ci & 7;
      int p = ((ch ^ (row & 7)) * 8);
      *(uint4*)(lA + row * 64 + p) = *(const uint4*)(Ab + (size_t)row * K + k0 + ch * 8);
      *(uint4*)(lB + row * 64 + p) = *(const uint4*)(Bb + (size_t)row * K + k0 + ch * 8);
    }
    __syncthreads();
#pragma unroll
    for (int kk = 0; kk < 2; ++kk) {
      bf16x8 af[4], bfr[4];
#pragma unroll
      for (int mf = 0; mf < 4; ++mf) {
        int r = wm * 64 + mf * 16 + lr;
        int ch = kk * 4 + lk;
        af[mf] = *(const bf16x8*)(lA + r * 64 + ((ch ^ (r & 7)) * 8));
      }
#pragma unroll
      for (int nf = 0; nf < 4; ++nf) {
        int r = wn * 64 + nf * 16 + lr;
        int ch = kk * 4 + lk;
        bfr[nf] = *(const bf16x8*)(lB + r * 64 + ((ch ^ (r & 7)) * 8));
      }
#pragma unroll
      for (int mf = 0; mf < 4; ++mf)
#pragma unroll
        for (int nf = 0; nf < 4; ++nf)
          acc[mf][nf] = __builtin_amdgcn_mfma_f32_16x16x32_bf16(af[mf], bfr[nf],
                                                                acc[mf][nf], 0, 0, 0);
    }
  }
  int rb = tmi * 128 + wm * 64;
  int cb = tni * 128 + wn * 64;
  if constexpr (EPI == 0) {
    bf16_t* D = (bf16_t*)Dst + (size_t)b * sD;
#pragma unroll
    for (int mf = 0; mf < 4; ++mf)
#pragma unroll
      for (int nf = 0; nf < 4; ++nf) {
        int r0 = rb + mf * 16 + lk * 4;
        int c = cb + nf * 16 + lr;
        bf16x4 v;
#pragma unroll
        for (int i = 0; i < 4; ++i) v[i] = (bf16_t)(acc[mf][nf][i] + bias[r0 + i]);
        *(bf16x4*)(D + (size_t)c * ldD + r0) = v;
      }
  } else if constexpr (EPI == 1) {
    bf16_t* D = (bf16_t*)Dst + (size_t)b * sD;
#pragma unroll
    for (int mf = 0; mf < 4; ++mf)
#pragma unroll
      for (int nf = 0; nf < 4; ++nf) {
        int r0 = rb + mf * 16 + lk * 4;
        int c = cb + nf * 16 + lr;
#pragma unroll
        for (int i = 0; i < 4; ++i)
          D[(size_t)(r0 + i) * ldD + c] = (bf16_t)(acc[mf][nf][i] + bias[r0 + i]);
      }
  } else {  // EPI == 4: transposed f32 store + resid + bias[c]
    float* D = (float*)Dst + (size_t)b * sD;
    const float* R = resid + (size_t)b * sR;
#pragma unroll
    for (int mf = 0; mf < 4; ++mf)
#pragma unroll
      for (int nf = 0; nf < 4; ++nf) {
        int r0 = rb + mf * 16 + lk * 4;
        int c = cb + nf * 16 + lr;
        float4 rv = *(const float4*)(R + (size_t)c * ldD + r0);
        float bc = bias[c];
        float4 o2 = make_float4(acc[mf][nf][0] + rv.x + bc, acc[mf][nf][1] + rv.y + bc,
                                acc[mf][nf][2] + rv.z + bc, acc[mf][nf][3] + rv.w + bc);
        *(float4*)(D + (size_t)c * ldD + r0) = o2;
      }
  }
}

extern "C" void kernel_launch(void* const* d_in, const int* in_sizes, int n_in,
                              void* d_out, int out_size, void* d_ws, size_t ws_size,
                              hipStream_t stream) {
  (void)in_sizes; (void)n_in; (void)out_size; (void)ws_size;
  const float* x = (const float*)d_in[0];
  const float* gamma = (const float*)d_in[1];
  const float* beta = (const float*)d_in[2];
  const float* wq = (const float*)d_in[3];
  const float* bq = (const float*)d_in[4];
  const float* wk = (const float*)d_in[5];
  const float* bk = (const float*)d_in[6];
  const float* wv = (const float*)d_in[7];
  const float* bv = (const float*)d_in[8];
  const float* wh = (const float*)d_in[9];
  const float* bh = (const float*)d_in[10];
  float* out = (float*)d_out;

  char* ws = (char*)d_ws;
  bf16_t* HN = (bf16_t*)(ws);                // Hn_t [B][N][C]; reused as O_t after fattn
  bf16_t* QT = (bf16_t*)(ws + 16777216);     // Q_t [B][N][C]
  bf16_t* KT = (bf16_t*)(ws + 33554432);     // K_t [B][N][C]
  bf16_t* VV = (bf16_t*)(ws + 50331648);     // V   [B][C][N]
  bf16_t* WB = (bf16_t*)(ws + 67108864);     // Wq|Wk|Wv|Wh bf16

  const long NC = (long)kN * kC;
  const long CN = (long)kC * kN;

  gn_fused_k<<<kB * 32, 256, 0, stream>>>(x, gamma, beta, HN);
  castw_k<<<256, 256, 0, stream>>>(wq, wk, wv, wh, WB);

  // Q_t[n][co] = (Wq . Hn)^T + bq
  gemm_k<0><<<kB * 2 * 8, 256, 0, stream>>>(WB, 0, HN, NC, QT, NC, bq, nullptr, 0,
                                            256, 256, 2, 8, 1.f);
  gemm_k<0><<<kB * 2 * 8, 256, 0, stream>>>(WB + 65536, 0, HN, NC, KT, NC, bk, nullptr, 0,
                                            256, 256, 2, 8, 1.f);
  // V[co][n]
  gemm_k<1><<<kB * 2 * 8, 256, 0, stream>>>(WB + 131072, 0, HN, NC, VV, CN, bv, nullptr, 0,
                                            256, 1024, 2, 8, 1.f);
  // fused attention -> O_t in HN
  fattn_k<<<256, 256, 0, stream>>>(QT, KT, VV, HN);
  // out[co][n] = x + (O_t . Wh^T)^T + bh
  gemm_k<4><<<kB * 8 * 2, 256, 0, stream>>>(HN, NC, WB + 196608, 0, out, CN, bh, x, CN,
                                            256, 1024, 8, 2, 1.f);
}